// Round 13
// baseline (291.829 us; speedup 1.0000x reference)
//
#include <hip/hip_runtime.h>

#define T 4096
#define K 4096
#define O 4096
#define E 4
#define BK 64
#define MAXT128 35

typedef __attribute__((ext_vector_type(8))) short bf16x8;
typedef __attribute__((ext_vector_type(4))) float f32x4;

__device__ __forceinline__ unsigned short f2bf(float f) {
  unsigned int u = __float_as_uint(f);
  u += 0x7fffu + ((u >> 16) & 1u);  // RNE
  return (unsigned short)(u >> 16);
}

// One block, 256 threads. perm, tile tables, persistent schedule
// (XCD 4x8 region map + remainder K-units; K-unit = 256 k = 4 BK-tiles).
__global__ void build_meta(const int* __restrict__ idx, int* __restrict__ perm,
                           int* __restrict__ meta, int4* __restrict__ t256,
                           int4* __restrict__ t128, int4* __restrict__ sched) {
  const int wave = threadIdx.x >> 6;
  const int lane = threadIdx.x & 63;
  __shared__ int s_off[E + 1];
  __shared__ int rtE[20], rtP[20], rtC[20];
  __shared__ int r_sh;
  int total = 0;
  for (int t0 = 0; t0 < T; t0 += 64)
    total += __popcll(__ballot(idx[t0 + lane] == wave));
  if (lane == 0) s_off[wave + 1] = total;
  __syncthreads();
  if (threadIdx.x == 0) {
    s_off[0] = 0;
    for (int e = 0; e < E; e++) s_off[e + 1] += s_off[e];
  }
  __syncthreads();
  int base = s_off[wave];
  const unsigned long long below = (1ull << lane) - 1ull;
  for (int t0 = 0; t0 < T; t0 += 64) {
    int e = idx[t0 + lane];
    unsigned long long m = __ballot(e == wave);
    if (e == wave) perm[base + __popcll(m & below)] = t0 + lane;
    base += __popcll(m);
  }
  if (threadIdx.x == 0) {
    int n = 0;
    for (int e = 0; e < E; e++) {
      int s = s_off[e], c = s_off[e + 1] - s;
      for (int ro = 0; ro < c; ro += 256) {
        rtE[n] = e; rtP[n] = s + ro; rtC[n] = (c - ro) < 256 ? (c - ro) : 256; n++;
      }
    }
    r_sh = n;
    meta[0] = n * 16;
    int n1 = 0;
    for (int e = 0; e < E; e++) {
      int s = s_off[e], c = s_off[e + 1] - s;
      for (int ro = 0; ro < c; ro += 128)
        t128[n1++] = make_int4(e, s + ro, (c - ro) < 128 ? (c - ro) : 128, 0);
    }
    for (; n1 < MAXT128; n1++) t128[n1] = make_int4(-1, 0, 0, 0);
  }
  __syncthreads();
  const int r = r_sh;  // rowtiles, 16..19
  for (int i = threadIdx.x; i < 16 * r; i += 256)
    t256[i] = make_int4(rtE[i >> 4], rtP[i >> 4], rtC[i >> 4], (i & 15) * 256);
  {
    const int b = threadIdx.x;
    const int ru = r - 16;
    const int xcd = b & 7, s = b >> 3;
    const int rt_ = 4 * (xcd >> 1) + (s >> 3);
    const int nt_ = 8 * (xcd & 1) + (s & 7);
    sched[b * 3 + 0] = make_int4(rt_ * 16 + nt_, 0, 16, 0);
    int sgi = 1, u0 = b * ru, u1 = u0 + ru;
    while (u0 < u1) {
      int tI = 256 + (u0 >> 4), q0 = u0 & 15;
      int avail = 16 - q0, want = u1 - u0;
      int take = want < avail ? want : avail;
      sched[b * 3 + sgi] = make_int4(tI, q0, take, 0);
      sgi++; u0 += take;
    }
    for (; sgi < 3; sgi++) sched[b * 3 + sgi] = make_int4(-1, 0, 0, 0);
  }
}

// Zero the output regions of remainder tiles (atomic-combine targets).
__global__ void zero_rem(const int* __restrict__ meta, const int4* __restrict__ t256,
                         const int* __restrict__ perm, float* __restrict__ out) {
  const int ntiles = meta[0];
  const int tI = 256 + (int)blockIdx.x / 16;
  if (tI >= ntiles) return;
  const int4 td = t256[tI];
  const int rt = (blockIdx.x & 15) * 16 + ((int)threadIdx.x >> 4);
  if (rt >= td.z) return;
  float4* p = (float4*)(out + (size_t)perm[td.y + rt] * O + td.w) + (threadIdx.x & 15) * 4;
  const float4 z = {0.f, 0.f, 0.f, 0.f};
  p[0] = z; p[1] = z; p[2] = z; p[3] = z;
}

// Cast W (fp32->bf16) and gather-cast x rows into expert-sorted order.
__global__ void convert_kernel(const float4* __restrict__ w4, const float* __restrict__ x,
                               const int* __restrict__ perm,
                               ushort4* __restrict__ wb4, ushort4* __restrict__ xg4) {
  const size_t NW4 = (size_t)E * O * K / 4;
  const size_t NX4 = (size_t)T * K / 4;
  const size_t stride = (size_t)gridDim.x * blockDim.x;
  const size_t t0 = (size_t)blockIdx.x * blockDim.x + threadIdx.x;
  for (size_t i = t0; i < NW4; i += stride) {
    float4 v = w4[i];
    wb4[i] = make_ushort4(f2bf(v.x), f2bf(v.y), f2bf(v.z), f2bf(v.w));
  }
  for (size_t j = t0; j < NX4; j += stride) {
    int p = (int)(j >> 10);
    int c = (int)(j & 1023);
    float4 v = *((const float4*)(x + (size_t)perm[p] * K) + c);
    xg4[j] = make_ushort4(f2bf(v.x), f2bf(v.y), f2bf(v.z), f2bf(v.w));
  }
}

// ------- persistent 256x256 grouped GEMM, quadrant-K64 phases (m201) -------
// 256 blocks (1/CU), <=3 (tile, K-range) segments from sched.
// LDS: 2 buffers x 4 slabs 16KB [A.kh0][A.kh1][B.kh0][B.kh1] = 128 KiB.
// Slab = [256r][32c] bf16 as 1024 16B-slots, 2-row-block XOR swizzle.
// Phase = one C-quadrant x full K=64: 16 MFMA per {BAR; lgkm0; setprio}
// sandwich, with A/B fragments RETAINED in registers across phases
// (reads per phase: 12 / 8 / 4 / 8). Staging: nxt.kh0 @ph1, nxt.kh1 @ph2
// (4 gloads each); single VM0 at ph4-end (loads ~2-3 phases old).
__global__ __launch_bounds__(512, 2)
void gemm8p(const unsigned short* __restrict__ xg, const unsigned short* __restrict__ wbb,
            const int* __restrict__ perm, const int4* __restrict__ t256,
            const int4* __restrict__ sched, float* __restrict__ out) {
  __shared__ unsigned short lds[65536];  // 128 KiB
  const int bid = blockIdx.x;
  const int tid = threadIdx.x;
  const int wid = tid >> 6, lane = tid & 63;
  const int wr = wid >> 2, wc = wid & 3;  // 2M x 4N waves; per-wave 128x64
  const int kc4 = lane >> 4;
  unsigned short* ldsw = &lds[wid * 512];  // wave-uniform stage base

#define GLL(gp, lp) __builtin_amdgcn_global_load_lds( \
    (const __attribute__((address_space(1))) void*)(gp), \
    (__attribute__((address_space(3))) void*)(lp), 16, 0, 0)
#define STAGE_A(bo, kh, ko) do { \
    GLL(srcA0 + (ko) + (kh) * 32, ldsw + (bo) + (kh) * 8192); \
    GLL(srcA1 + (ko) + (kh) * 32, ldsw + (bo) + (kh) * 8192 + 4096); \
  } while (0)
#define STAGE_B(bo, kh, ko) do { \
    GLL(srcB0 + (ko) + (kh) * 32, ldsw + (bo) + 16384 + (kh) * 8192); \
    GLL(srcB1 + (ko) + (kh) * 32, ldsw + (bo) + 16384 + (kh) * 8192 + 4096); \
  } while (0)
// A fragments for row-half mh, BOTH kh: afk[ks][mi] (8 reads)
#define LOADA2(bo, mh) do { _Pragma("unroll") \
    for (int ks = 0; ks < 2; ++ks) _Pragma("unroll") \
      for (int mi = 0; mi < 4; ++mi) \
        afk[ks][mi] = *(const bf16x8*)&lds[(bo) + ks * 8192 + aoff[mh][mi]]; } while (0)
// B fragments for ni pair {nb, nb+1}, BOTH kh: bfk[ks][j] (4 reads)
#define LOADB2(bo, nb) do { _Pragma("unroll") \
    for (int ks = 0; ks < 2; ++ks) _Pragma("unroll") \
      for (int j = 0; j < 2; ++j) \
        bfk[ks][j] = *(const bf16x8*)&lds[(bo) + 16384 + ks * 8192 + boff[(nb) + j]]; } while (0)
// One C-quadrant x K=64: 2ks x 4mi x 2j = 16 MFMA
#define MF16(mib, nib) do { _Pragma("unroll") \
    for (int ks = 0; ks < 2; ++ks) _Pragma("unroll") \
      for (int mi = 0; mi < 4; ++mi) _Pragma("unroll") \
        for (int j = 0; j < 2; ++j) \
          acc[(mib) + mi][(nib) + j] = __builtin_amdgcn_mfma_f32_16x16x32_bf16( \
              afk[ks][mi], bfk[ks][j], acc[(mib) + mi][(nib) + j], 0, 0, 0); } while (0)
#define BAR() do { __builtin_amdgcn_s_barrier(); asm volatile("" ::: "memory"); } while (0)
#define LGKM0() asm volatile("s_waitcnt lgkmcnt(0)" ::: "memory")
#define LGKM8() asm volatile("s_waitcnt lgkmcnt(8)" ::: "memory")
#define VM0() asm volatile("s_waitcnt vmcnt(0)" ::: "memory")
#define PRIO1() __builtin_amdgcn_s_setprio(1)
#define PRIO0() __builtin_amdgcn_s_setprio(0)

// One K-tile = 4 quadrant phases. Operand retention: bfk held across
// ph1->ph2 (mh sweep), afk held across ph2->ph3 (nh sweep).
#define KTILE(C, X, koe) do { \
    const int ko = (koe); \
    /* ph1 (mh0, ni01): 12 reads; stage nxt.kh0 */ \
    LOADA2(C, 0); LOADB2(C, 0); \
    STAGE_A(X, 0, ko); STAGE_B(X, 0, ko); \
    LGKM8(); BAR(); LGKM0(); \
    PRIO1(); MF16(0, 0); PRIO0(); \
    BAR(); \
    /* ph2 (mh1, ni01): 8 reads (bfk retained); stage nxt.kh1 */ \
    LOADA2(C, 1); \
    STAGE_A(X, 1, ko); STAGE_B(X, 1, ko); \
    BAR(); LGKM0(); \
    PRIO1(); MF16(4, 0); PRIO0(); \
    BAR(); \
    /* ph3 (mh1, ni23): 4 reads (afk retained) */ \
    LOADB2(C, 2); \
    BAR(); LGKM0(); \
    PRIO1(); MF16(4, 2); PRIO0(); \
    BAR(); \
    /* ph4 (mh0, ni23): 8 reads (bfk retained) */ \
    LOADA2(C, 0); \
    BAR(); LGKM0(); \
    PRIO1(); MF16(0, 2); PRIO0(); \
    VM0(); BAR(); \
  } while (0)

  // swizzled fragment offsets (ushort units) — segment-invariant
  int aoff[2][4], boff[4];
#pragma unroll
  for (int mh = 0; mh < 2; ++mh)
#pragma unroll
    for (int mi = 0; mi < 4; ++mi) {
      int r = wr * 128 + mh * 64 + mi * 16 + (lane & 15);
      aoff[mh][mi] = (((r >> 1) << 3) + (((((r & 1) << 2) | kc4)) ^ ((r >> 1) & 7))) * 8;
    }
#pragma unroll
  for (int ni = 0; ni < 4; ++ni) {
    int r = wc * 64 + ni * 16 + (lane & 15);
    boff[ni] = (((r >> 1) << 3) + (((((r & 1) << 2) | kc4)) ^ ((r >> 1) & 7))) * 8;
  }

  for (int sg = 0; sg < 3; ++sg) {
    const int4 sd = sched[bid * 3 + sg];
    if (sd.x < 0) break;
    const int4 td = t256[sd.x];
    const int e = td.x, p0 = td.y, rc = td.z, n0 = td.w;
    const int kt0 = sd.y << 2;   // first BK-tile
    const int nt = sd.z << 2;    // BK-tiles in segment (multiple of 4)

    // staging source decode (slot -> logical row/c4, inverse of read swizzle)
    const unsigned short *srcA0, *srcA1, *srcB0, *srcB1;
    {
      const unsigned short* wB = wbb + (size_t)e * O * K + (size_t)n0 * K;
      int s0 = tid, s1 = 512 + tid;
      int b0 = s0 >> 3, v0 = (s0 & 7) ^ (b0 & 7);
      int r0 = b0 * 2 + (v0 >> 2), c0 = v0 & 3;
      int b1 = s1 >> 3, v1 = (s1 & 7) ^ (b1 & 7);
      int r1 = b1 * 2 + (v1 >> 2), c1 = v1 & 3;
      int ra0 = r0 < rc ? r0 : rc - 1;
      int ra1 = r1 < rc ? r1 : rc - 1;
      srcA0 = xg + (size_t)(p0 + ra0) * K + c0 * 8;
      srcA1 = xg + (size_t)(p0 + ra1) * K + c1 * 8;
      srcB0 = wB + (size_t)r0 * K + c0 * 8;
      srcB1 = wB + (size_t)r1 * K + c1 * 8;
    }

    f32x4 acc[8][4] = {};
    bf16x8 afk[2][4], bfk[2][2];

    const int kb = kt0 << 6;
    STAGE_A(0, 0, kb); STAGE_B(0, 0, kb);
    STAGE_A(0, 1, kb); STAGE_B(0, 1, kb);
    VM0(); BAR();

    for (int tp = 0; tp < nt; tp += 2) {
      KTILE(0, 32768, ((tp + 1 < nt ? tp + 1 : tp) + kt0) << 6);
      KTILE(32768, 0, ((tp + 2 < nt ? tp + 2 : tp + 1) + kt0) << 6);
    }
    VM0();  // drain stale prefetch before epilogue / next segment's staging

    // epilogue: C layout col=lane&15, row=(lane>>4)*4+reg
    if (sd.z == 16) {
#pragma unroll
      for (int mh = 0; mh < 2; ++mh)
#pragma unroll
        for (int mi = 0; mi < 4; ++mi) {
          const int rbase = wr * 128 + mh * 64 + mi * 16 + (lane >> 4) * 4;
#pragma unroll
          for (int reg = 0; reg < 4; ++reg) {
            const int pr = rbase + reg;
            if (pr < rc) {
              float* orow = out + (size_t)perm[p0 + pr] * O + n0 + wc * 64 + (lane & 15);
#pragma unroll
              for (int ni = 0; ni < 4; ++ni) orow[ni * 16] = acc[mh * 4 + mi][ni][reg];
            }
          }
        }
    } else {
#pragma unroll
      for (int mh = 0; mh < 2; ++mh)
#pragma unroll
        for (int mi = 0; mi < 4; ++mi) {
          const int rbase = wr * 128 + mh * 64 + mi * 16 + (lane >> 4) * 4;
#pragma unroll
          for (int reg = 0; reg < 4; ++reg) {
            const int pr = rbase + reg;
            if (pr < rc) {
              float* orow = out + (size_t)perm[p0 + pr] * O + n0 + wc * 64 + (lane & 15);
#pragma unroll
              for (int ni = 0; ni < 4; ++ni)
                unsafeAtomicAdd(&orow[ni * 16], acc[mh * 4 + mi][ni][reg]);
            }
          }
        }
    }
  }
}

// ---------------- fallback (small ws): 128x128 fp32-source reg-staged ----------------
__global__ __launch_bounds__(256)
void gemm_fb(const float* __restrict__ xf, const float* __restrict__ wf,
             const int* __restrict__ perm, const int4* __restrict__ tiles,
             float* __restrict__ out) {
  __shared__ unsigned short lds_a[128 * 64];
  __shared__ unsigned short lds_b[128 * 64];
  const int4 td = tiles[blockIdx.x];
  if (td.x < 0) return;
  const int e = td.x, p0 = td.y, rc = td.z;
  const int n0 = blockIdx.y * 128;
  const int wave = threadIdx.x >> 6, lane = threadIdx.x & 63;
  const int wr = wave >> 1, wc = wave & 1;
  f32x4 acc[4][4] = {};
  const float* wf_base = wf + (size_t)e * O * K + (size_t)n0 * K;
  for (int k0 = 0; k0 < K; k0 += 64) {
    if (k0) __syncthreads();
#pragma unroll
    for (int i = 0; i < 8; i++) {
      int l4 = i * 256 + (int)threadIdx.x;
      int row = l4 >> 4;
      int c4 = (l4 & 15) << 2;
      int ra = row < rc ? row : (rc - 1);
      const float4 va = *(const float4*)(xf + (size_t)perm[p0 + ra] * K + k0 + c4);
      *(ushort4*)&lds_a[row * 64 + c4] = make_ushort4(f2bf(va.x), f2bf(va.y), f2bf(va.z), f2bf(va.w));
      const float4 vb = *(const float4*)(wf_base + (size_t)row * K + k0 + c4);
      *(ushort4*)&lds_b[row * 64 + c4] = make_ushort4(f2bf(vb.x), f2bf(vb.y), f2bf(vb.z), f2bf(vb.w));
    }
    __syncthreads();
#pragma unroll
    for (int ks = 0; ks < 2; ks++) {
      bf16x8 a2[4], b2[4];
#pragma unroll
      for (int mi = 0; mi < 4; mi++)
        a2[mi] = *(const bf16x8*)&lds_a[(wr * 64 + mi * 16 + (lane & 15)) * 64 + ks * 32 + (lane >> 4) * 8];
#pragma unroll
      for (int ni = 0; ni < 4; ni++)
        b2[ni] = *(const bf16x8*)&lds_b[(wc * 64 + ni * 16 + (lane & 15)) * 64 + ks * 32 + (lane >> 4) * 8];
#pragma unroll
      for (int mi = 0; mi < 4; mi++)
#pragma unroll
        for (int ni = 0; ni < 4; ni++)
          acc[mi][ni] = __builtin_amdgcn_mfma_f32_16x16x32_bf16(a2[mi], b2[ni], acc[mi][ni], 0, 0, 0);
    }
  }
#pragma unroll
  for (int mi = 0; mi < 4; mi++) {
    const int rb = wr * 64 + mi * 16 + (lane >> 4) * 4;
#pragma unroll
    for (int reg = 0; reg < 4; reg++) {
      const int rt = rb + reg;
      if (rt < rc) {
        float* orow = out + (size_t)perm[p0 + rt] * O + n0 + wc * 64 + (lane & 15);
#pragma unroll
        for (int ni = 0; ni < 4; ni++) orow[ni * 16] = acc[mi][ni][reg];
      }
    }
  }
}

extern "C" void kernel_launch(void* const* d_in, const int* in_sizes, int n_in,
                              void* d_out, int out_size, void* d_ws, size_t ws_size,
                              hipStream_t stream) {
  const float* x = (const float*)d_in[0];
  const float* w = (const float*)d_in[1];
  const int* idx = (const int*)d_in[2];
  float* out = (float*)d_out;
  char* ws = (char*)d_ws;

  int* perm = (int*)ws;                        // 16 KB
  int* meta = (int*)(ws + 16384);              // 16 B
  int4* t256 = (int4*)(ws + 16640);            // 4864 B
  int4* t128 = (int4*)(ws + 22528);            // 560 B
  int4* sched = (int4*)(ws + 24576);           // 12 KB
  unsigned short* xg = (unsigned short*)(ws + 65536);          // 32 MB bf16
  unsigned short* wb = xg + (size_t)T * K;                     // 128 MB bf16
  const size_t need = 65536 + (size_t)T * K * 2 + (size_t)E * O * K * 2;

  build_meta<<<1, 256, 0, stream>>>(idx, perm, meta, t256, t128, sched);
  if (ws_size >= need) {
    zero_rem<<<768, 256, 0, stream>>>(meta, t256, perm, out);
    convert_kernel<<<4096, 256, 0, stream>>>((const float4*)w, x, perm,
                                             (ushort4*)wb, (ushort4*)xg);
    gemm8p<<<256, 512, 0, stream>>>(xg, wb, perm, t256, sched, out);
  } else {
    gemm_fb<<<dim3(MAXT128, 32), 256, 0, stream>>>(x, w, perm, t128, out);
  }
}

// Round 14
// 269.105 us; speedup vs baseline: 1.0844x; 1.0844x over previous
//
#include <hip/hip_runtime.h>

#define T 4096
#define K 4096
#define O 4096
#define E 4
#define BK 64
#define MAXT128 35

typedef __attribute__((ext_vector_type(8))) short bf16x8;
typedef __attribute__((ext_vector_type(4))) float f32x4;

__device__ __forceinline__ unsigned short f2bf(float f) {
  unsigned int u = __float_as_uint(f);
  u += 0x7fffu + ((u >> 16) & 1u);  // RNE
  return (unsigned short)(u >> 16);
}

// One block, 256 threads. perm, tile tables, persistent schedule
// (XCD 4x8 region map + remainder K-units; K-unit = 256 k = 4 BK-tiles).
__global__ void build_meta(const int* __restrict__ idx, int* __restrict__ perm,
                           int* __restrict__ meta, int4* __restrict__ t256,
                           int4* __restrict__ t128, int4* __restrict__ sched) {
  const int wave = threadIdx.x >> 6;
  const int lane = threadIdx.x & 63;
  __shared__ int s_off[E + 1];
  __shared__ int rtE[20], rtP[20], rtC[20];
  __shared__ int r_sh;
  int total = 0;
  for (int t0 = 0; t0 < T; t0 += 64)
    total += __popcll(__ballot(idx[t0 + lane] == wave));
  if (lane == 0) s_off[wave + 1] = total;
  __syncthreads();
  if (threadIdx.x == 0) {
    s_off[0] = 0;
    for (int e = 0; e < E; e++) s_off[e + 1] += s_off[e];
  }
  __syncthreads();
  int base = s_off[wave];
  const unsigned long long below = (1ull << lane) - 1ull;
  for (int t0 = 0; t0 < T; t0 += 64) {
    int e = idx[t0 + lane];
    unsigned long long m = __ballot(e == wave);
    if (e == wave) perm[base + __popcll(m & below)] = t0 + lane;
    base += __popcll(m);
  }
  if (threadIdx.x == 0) {
    int n = 0;
    for (int e = 0; e < E; e++) {
      int s = s_off[e], c = s_off[e + 1] - s;
      for (int ro = 0; ro < c; ro += 256) {
        rtE[n] = e; rtP[n] = s + ro; rtC[n] = (c - ro) < 256 ? (c - ro) : 256; n++;
      }
    }
    r_sh = n;
    meta[0] = n * 16;
    int n1 = 0;
    for (int e = 0; e < E; e++) {
      int s = s_off[e], c = s_off[e + 1] - s;
      for (int ro = 0; ro < c; ro += 128)
        t128[n1++] = make_int4(e, s + ro, (c - ro) < 128 ? (c - ro) : 128, 0);
    }
    for (; n1 < MAXT128; n1++) t128[n1] = make_int4(-1, 0, 0, 0);
  }
  __syncthreads();
  const int r = r_sh;  // rowtiles, 16..19
  for (int i = threadIdx.x; i < 16 * r; i += 256)
    t256[i] = make_int4(rtE[i >> 4], rtP[i >> 4], rtC[i >> 4], (i & 15) * 256);
  {
    const int b = threadIdx.x;
    const int ru = r - 16;
    const int xcd = b & 7, s = b >> 3;
    const int rt_ = 4 * (xcd >> 1) + (s >> 3);
    const int nt_ = 8 * (xcd & 1) + (s & 7);
    sched[b * 3 + 0] = make_int4(rt_ * 16 + nt_, 0, 16, 0);
    int sgi = 1, u0 = b * ru, u1 = u0 + ru;
    while (u0 < u1) {
      int tI = 256 + (u0 >> 4), q0 = u0 & 15;
      int avail = 16 - q0, want = u1 - u0;
      int take = want < avail ? want : avail;
      sched[b * 3 + sgi] = make_int4(tI, q0, take, 0);
      sgi++; u0 += take;
    }
    for (; sgi < 3; sgi++) sched[b * 3 + sgi] = make_int4(-1, 0, 0, 0);
  }
}

// Zero the output regions of remainder tiles (atomic-combine targets).
__global__ void zero_rem(const int* __restrict__ meta, const int4* __restrict__ t256,
                         const int* __restrict__ perm, float* __restrict__ out) {
  const int ntiles = meta[0];
  const int tI = 256 + (int)blockIdx.x / 16;
  if (tI >= ntiles) return;
  const int4 td = t256[tI];
  const int rt = (blockIdx.x & 15) * 16 + ((int)threadIdx.x >> 4);
  if (rt >= td.z) return;
  float4* p = (float4*)(out + (size_t)perm[td.y + rt] * O + td.w) + (threadIdx.x & 15) * 4;
  const float4 z = {0.f, 0.f, 0.f, 0.f};
  p[0] = z; p[1] = z; p[2] = z; p[3] = z;
}

// Cast W (fp32->bf16) and gather-cast x rows into expert-sorted order.
// Split branch-free loops (W path is 80% of iterations); 4096 blocks.
__global__ void convert_kernel(const float4* __restrict__ w4, const float* __restrict__ x,
                               const int* __restrict__ perm,
                               ushort4* __restrict__ wb4, ushort4* __restrict__ xg4) {
  const size_t NW4 = (size_t)E * O * K / 4;
  const size_t NX4 = (size_t)T * K / 4;
  const size_t stride = (size_t)gridDim.x * blockDim.x;
  const size_t t0 = (size_t)blockIdx.x * blockDim.x + threadIdx.x;
  for (size_t i = t0; i < NW4; i += stride) {
    float4 v = w4[i];
    wb4[i] = make_ushort4(f2bf(v.x), f2bf(v.y), f2bf(v.z), f2bf(v.w));
  }
  for (size_t j = t0; j < NX4; j += stride) {
    int p = (int)(j >> 10);
    int c = (int)(j & 1023);
    float4 v = *((const float4*)(x + (size_t)perm[p] * K) + c);
    xg4[j] = make_ushort4(f2bf(v.x), f2bf(v.y), f2bf(v.z), f2bf(v.w));
  }
}

// ---------------- persistent 256x256 minimal-sync grouped GEMM (16x16x32) ---
// 256 blocks (1/CU), each runs <=3 (tile, K-range) segments from sched.
// LDS per buffer: 4 slabs of 16KB [A.kh0][A.kh1][B.kh0][B.kh1], 2 buffers.
// Slab = [256 rows][32 bf16] as 1024 16B-slots, 2-row-block XOR swizzle.
// MINIMAL SYNC: exactly 2 {counted-vmcnt; barrier} points per K-tile (the
// publications of the two staged halves). No lgkm drains: compiler emits
// per-dependency counted lgkmcnt; wave skew overlaps one wave's LDS read
// storm with co-resident waves' MFMA storms (setprio arbitrates).
__global__ __launch_bounds__(512, 2)
void gemm8p(const unsigned short* __restrict__ xg, const unsigned short* __restrict__ wbb,
            const int* __restrict__ perm, const int4* __restrict__ t256,
            const int4* __restrict__ sched, float* __restrict__ out) {
  __shared__ unsigned short lds[65536];  // 128 KiB
  const int bid = blockIdx.x;
  const int tid = threadIdx.x;
  const int wid = tid >> 6, lane = tid & 63;
  const int wr = wid >> 2, wc = wid & 3;  // 2M x 4N waves; per-wave 128x64
  const int kc4 = lane >> 4;
  unsigned short* ldsw = &lds[wid * 512];  // wave-uniform stage base

#define GLL(gp, lp) __builtin_amdgcn_global_load_lds( \
    (const __attribute__((address_space(1))) void*)(gp), \
    (__attribute__((address_space(3))) void*)(lp), 16, 0, 0)
#define STAGE_A(bo, kh, ko) do { \
    GLL(srcA0 + (ko) + (kh) * 32, ldsw + (bo) + (kh) * 8192); \
    GLL(srcA1 + (ko) + (kh) * 32, ldsw + (bo) + (kh) * 8192 + 4096); \
  } while (0)
#define STAGE_B(bo, kh, ko) do { \
    GLL(srcB0 + (ko) + (kh) * 32, ldsw + (bo) + 16384 + (kh) * 8192); \
    GLL(srcB1 + (ko) + (kh) * 32, ldsw + (bo) + 16384 + (kh) * 8192 + 4096); \
  } while (0)
#define LOADA(dst, bo, ks, mh) do { _Pragma("unroll") \
    for (int mi = 0; mi < 4; ++mi) \
      dst[mi] = *(const bf16x8*)&lds[(bo) + (ks) * 8192 + aoff[mh][mi]]; } while (0)
#define LOADB(dst, bo, ks) do { _Pragma("unroll") \
    for (int ni = 0; ni < 4; ++ni) \
      dst[ni] = *(const bf16x8*)&lds[(bo) + 16384 + (ks) * 8192 + boff[ni]]; } while (0)
#define MFMA16(A, B, mh) do { _Pragma("unroll") \
    for (int mi = 0; mi < 4; ++mi) _Pragma("unroll") \
      for (int ni = 0; ni < 4; ++ni) \
        acc[(mh) * 4 + mi][ni] = __builtin_amdgcn_mfma_f32_16x16x32_bf16( \
            A[mi], B[ni], acc[(mh) * 4 + mi][ni], 0, 0, 0); } while (0)
#define BAR() do { __builtin_amdgcn_s_barrier(); asm volatile("" ::: "memory"); } while (0)
#define VM4() asm volatile("s_waitcnt vmcnt(4)" ::: "memory")
#define VM0() asm volatile("s_waitcnt vmcnt(0)" ::: "memory")
#define PRIO1() __builtin_amdgcn_s_setprio(1)
#define PRIO0() __builtin_amdgcn_s_setprio(0)

// One K-tile = 2 scheduling regions, each ends with its half-publication.
// Sync#1 drains prev-tile A1,B1 (cur.kh1 published for half 2).
// Sync#2 drains this tile's A0x,B0x (nxt.kh0 published for next tile).
#define KTILE(C, X, koe) do { \
    const int ko = (koe); \
    LOADA(afP, C, 0, 0); LOADB(bfP, C, 0); \
    STAGE_A(X, 0, ko); \
    PRIO1(); MFMA16(afP, bfP, 0); PRIO0(); \
    LOADA(afQ, C, 0, 1); \
    STAGE_B(X, 0, ko); \
    PRIO1(); MFMA16(afQ, bfP, 1); PRIO0(); \
    VM4(); BAR(); \
    LOADA(afP, C, 1, 0); LOADB(bfQ, C, 1); \
    STAGE_A(X, 1, ko); \
    PRIO1(); MFMA16(afP, bfQ, 0); PRIO0(); \
    LOADA(afQ, C, 1, 1); \
    STAGE_B(X, 1, ko); \
    PRIO1(); MFMA16(afQ, bfQ, 1); PRIO0(); \
    VM4(); BAR(); \
  } while (0)

  // swizzled fragment offsets (ushort units) — segment-invariant
  int aoff[2][4], boff[4];
#pragma unroll
  for (int mh = 0; mh < 2; ++mh)
#pragma unroll
    for (int mi = 0; mi < 4; ++mi) {
      int r = wr * 128 + mh * 64 + mi * 16 + (lane & 15);
      aoff[mh][mi] = (((r >> 1) << 3) + (((((r & 1) << 2) | kc4)) ^ ((r >> 1) & 7))) * 8;
    }
#pragma unroll
  for (int ni = 0; ni < 4; ++ni) {
    int r = wc * 64 + ni * 16 + (lane & 15);
    boff[ni] = (((r >> 1) << 3) + (((((r & 1) << 2) | kc4)) ^ ((r >> 1) & 7))) * 8;
  }

  for (int sg = 0; sg < 3; ++sg) {
    const int4 sd = sched[bid * 3 + sg];
    if (sd.x < 0) break;
    const int4 td = t256[sd.x];
    const int e = td.x, p0 = td.y, rc = td.z, n0 = td.w;
    const int kt0 = sd.y << 2;   // first BK-tile
    const int nt = sd.z << 2;    // BK-tiles in segment (multiple of 4)

    // staging source decode (slot -> logical row/c4, inverse of read swizzle)
    const unsigned short *srcA0, *srcA1, *srcB0, *srcB1;
    {
      const unsigned short* wB = wbb + (size_t)e * O * K + (size_t)n0 * K;
      int s0 = tid, s1 = 512 + tid;
      int b0 = s0 >> 3, v0 = (s0 & 7) ^ (b0 & 7);
      int r0 = b0 * 2 + (v0 >> 2), c0 = v0 & 3;
      int b1 = s1 >> 3, v1 = (s1 & 7) ^ (b1 & 7);
      int r1 = b1 * 2 + (v1 >> 2), c1 = v1 & 3;
      int ra0 = r0 < rc ? r0 : rc - 1;
      int ra1 = r1 < rc ? r1 : rc - 1;
      srcA0 = xg + (size_t)(p0 + ra0) * K + c0 * 8;
      srcA1 = xg + (size_t)(p0 + ra1) * K + c1 * 8;
      srcB0 = wB + (size_t)r0 * K + c0 * 8;
      srcB1 = wB + (size_t)r1 * K + c1 * 8;
    }

    f32x4 acc[8][4] = {};
    bf16x8 afP[4], afQ[4], bfP[4], bfQ[4];

    const int kb = kt0 << 6;
    STAGE_A(0, 0, kb); STAGE_B(0, 0, kb);
    STAGE_A(0, 1, kb); STAGE_B(0, 1, kb);
    VM4(); BAR();   // kh0 published; kh1 (A1,B1) drains at first in-loop sync

    for (int tp = 0; tp < nt; tp += 2) {
      KTILE(0, 32768, ((tp + 1 < nt ? tp + 1 : tp) + kt0) << 6);
      KTILE(32768, 0, ((tp + 2 < nt ? tp + 2 : tp + 1) + kt0) << 6);
    }
    VM0();  // drain stale prefetch before epilogue / next segment's staging

    // epilogue: C layout col=lane&15, row=(lane>>4)*4+reg
    if (sd.z == 16) {
#pragma unroll
      for (int mh = 0; mh < 2; ++mh)
#pragma unroll
        for (int mi = 0; mi < 4; ++mi) {
          const int rbase = wr * 128 + mh * 64 + mi * 16 + (lane >> 4) * 4;
#pragma unroll
          for (int reg = 0; reg < 4; ++reg) {
            const int pr = rbase + reg;
            if (pr < rc) {
              float* orow = out + (size_t)perm[p0 + pr] * O + n0 + wc * 64 + (lane & 15);
#pragma unroll
              for (int ni = 0; ni < 4; ++ni) orow[ni * 16] = acc[mh * 4 + mi][ni][reg];
            }
          }
        }
    } else {
#pragma unroll
      for (int mh = 0; mh < 2; ++mh)
#pragma unroll
        for (int mi = 0; mi < 4; ++mi) {
          const int rbase = wr * 128 + mh * 64 + mi * 16 + (lane >> 4) * 4;
#pragma unroll
          for (int reg = 0; reg < 4; ++reg) {
            const int pr = rbase + reg;
            if (pr < rc) {
              float* orow = out + (size_t)perm[p0 + pr] * O + n0 + wc * 64 + (lane & 15);
#pragma unroll
              for (int ni = 0; ni < 4; ++ni)
                unsafeAtomicAdd(&orow[ni * 16], acc[mh * 4 + mi][ni][reg]);
            }
          }
        }
    }
  }
}

// ---------------- fallback (small ws): 128x128 fp32-source reg-staged ----------------
__global__ __launch_bounds__(256)
void gemm_fb(const float* __restrict__ xf, const float* __restrict__ wf,
             const int* __restrict__ perm, const int4* __restrict__ tiles,
             float* __restrict__ out) {
  __shared__ unsigned short lds_a[128 * 64];
  __shared__ unsigned short lds_b[128 * 64];
  const int4 td = tiles[blockIdx.x];
  if (td.x < 0) return;
  const int e = td.x, p0 = td.y, rc = td.z;
  const int n0 = blockIdx.y * 128;
  const int wave = threadIdx.x >> 6, lane = threadIdx.x & 63;
  const int wr = wave >> 1, wc = wave & 1;
  f32x4 acc[4][4] = {};
  const float* wf_base = wf + (size_t)e * O * K + (size_t)n0 * K;
  for (int k0 = 0; k0 < K; k0 += 64) {
    if (k0) __syncthreads();
#pragma unroll
    for (int i = 0; i < 8; i++) {
      int l4 = i * 256 + (int)threadIdx.x;
      int row = l4 >> 4;
      int c4 = (l4 & 15) << 2;
      int ra = row < rc ? row : (rc - 1);
      const float4 va = *(const float4*)(xf + (size_t)perm[p0 + ra] * K + k0 + c4);
      *(ushort4*)&lds_a[row * 64 + c4] = make_ushort4(f2bf(va.x), f2bf(va.y), f2bf(va.z), f2bf(va.w));
      const float4 vb = *(const float4*)(wf_base + (size_t)row * K + k0 + c4);
      *(ushort4*)&lds_b[row * 64 + c4] = make_ushort4(f2bf(vb.x), f2bf(vb.y), f2bf(vb.z), f2bf(vb.w));
    }
    __syncthreads();
#pragma unroll
    for (int ks = 0; ks < 2; ks++) {
      bf16x8 a2[4], b2[4];
#pragma unroll
      for (int mi = 0; mi < 4; mi++)
        a2[mi] = *(const bf16x8*)&lds_a[(wr * 64 + mi * 16 + (lane & 15)) * 64 + ks * 32 + (lane >> 4) * 8];
#pragma unroll
      for (int ni = 0; ni < 4; ni++)
        b2[ni] = *(const bf16x8*)&lds_b[(wc * 64 + ni * 16 + (lane & 15)) * 64 + ks * 32 + (lane >> 4) * 8];
#pragma unroll
      for (int mi = 0; mi < 4; mi++)
#pragma unroll
        for (int ni = 0; ni < 4; ni++)
          acc[mi][ni] = __builtin_amdgcn_mfma_f32_16x16x32_bf16(a2[mi], b2[ni], acc[mi][ni], 0, 0, 0);
    }
  }
#pragma unroll
  for (int mi = 0; mi < 4; mi++) {
    const int rb = wr * 64 + mi * 16 + (lane >> 4) * 4;
#pragma unroll
    for (int reg = 0; reg < 4; reg++) {
      const int rt = rb + reg;
      if (rt < rc) {
        float* orow = out + (size_t)perm[p0 + rt] * O + n0 + wc * 64 + (lane & 15);
#pragma unroll
        for (int ni = 0; ni < 4; ni++) orow[ni * 16] = acc[mi][ni][reg];
      }
    }
  }
}

extern "C" void kernel_launch(void* const* d_in, const int* in_sizes, int n_in,
                              void* d_out, int out_size, void* d_ws, size_t ws_size,
                              hipStream_t stream) {
  const float* x = (const float*)d_in[0];
  const float* w = (const float*)d_in[1];
  const int* idx = (const int*)d_in[2];
  float* out = (float*)d_out;
  char* ws = (char*)d_ws;

  int* perm = (int*)ws;                        // 16 KB
  int* meta = (int*)(ws + 16384);              // 16 B
  int4* t256 = (int4*)(ws + 16640);            // 4864 B
  int4* t128 = (int4*)(ws + 22528);            // 560 B
  int4* sched = (int4*)(ws + 24576);           // 12 KB
  unsigned short* xg = (unsigned short*)(ws + 65536);          // 32 MB bf16
  unsigned short* wb = xg + (size_t)T * K;                     // 128 MB bf16
  const size_t need = 65536 + (size_t)T * K * 2 + (size_t)E * O * K * 2;

  build_meta<<<1, 256, 0, stream>>>(idx, perm, meta, t256, t128, sched);
  if (ws_size >= need) {
    zero_rem<<<768, 256, 0, stream>>>(meta, t256, perm, out);
    convert_kernel<<<4096, 256, 0, stream>>>((const float4*)w, x, perm,
                                             (ushort4*)wb, (ushort4*)xg);
    gemm8p<<<256, 512, 0, stream>>>(xg, wb, perm, t256, sched, out);
  } else {
    gemm_fb<<<dim3(MAXT128, 32), 256, 0, stream>>>(x, w, perm, t128, out);
  }
}

// Round 15
// 268.258 us; speedup vs baseline: 1.0879x; 1.0032x over previous
//
#include <hip/hip_runtime.h>

#define T 4096
#define K 4096
#define O 4096
#define E 4
#define BK 64
#define MAXT128 35

typedef __attribute__((ext_vector_type(8))) short bf16x8;
typedef __attribute__((ext_vector_type(8))) unsigned short ushort8;
typedef __attribute__((ext_vector_type(4))) float f32x4;

__device__ __forceinline__ unsigned short f2bf(float f) {
  unsigned int u = __float_as_uint(f);
  u += 0x7fffu + ((u >> 16) & 1u);  // RNE
  return (unsigned short)(u >> 16);
}

__device__ __forceinline__ ushort8 cvt8(float4 a, float4 b) {
  ushort8 r;
  r[0] = f2bf(a.x); r[1] = f2bf(a.y); r[2] = f2bf(a.z); r[3] = f2bf(a.w);
  r[4] = f2bf(b.x); r[5] = f2bf(b.y); r[6] = f2bf(b.z); r[7] = f2bf(b.w);
  return r;
}

// One block, 256 threads. perm, tile tables, persistent schedule
// (XCD 4x8 region map + remainder K-units; K-unit = 256 k = 4 BK-tiles).
__global__ void build_meta(const int* __restrict__ idx, int* __restrict__ perm,
                           int* __restrict__ meta, int4* __restrict__ t256,
                           int4* __restrict__ t128, int4* __restrict__ sched) {
  const int wave = threadIdx.x >> 6;
  const int lane = threadIdx.x & 63;
  __shared__ int s_off[E + 1];
  __shared__ int rtE[20], rtP[20], rtC[20];
  __shared__ int r_sh;
  int total = 0;
  for (int t0 = 0; t0 < T; t0 += 64)
    total += __popcll(__ballot(idx[t0 + lane] == wave));
  if (lane == 0) s_off[wave + 1] = total;
  __syncthreads();
  if (threadIdx.x == 0) {
    s_off[0] = 0;
    for (int e = 0; e < E; e++) s_off[e + 1] += s_off[e];
  }
  __syncthreads();
  int base = s_off[wave];
  const unsigned long long below = (1ull << lane) - 1ull;
  for (int t0 = 0; t0 < T; t0 += 64) {
    int e = idx[t0 + lane];
    unsigned long long m = __ballot(e == wave);
    if (e == wave) perm[base + __popcll(m & below)] = t0 + lane;
    base += __popcll(m);
  }
  if (threadIdx.x == 0) {
    int n = 0;
    for (int e = 0; e < E; e++) {
      int s = s_off[e], c = s_off[e + 1] - s;
      for (int ro = 0; ro < c; ro += 256) {
        rtE[n] = e; rtP[n] = s + ro; rtC[n] = (c - ro) < 256 ? (c - ro) : 256; n++;
      }
    }
    r_sh = n;
    meta[0] = n * 16;
    int n1 = 0;
    for (int e = 0; e < E; e++) {
      int s = s_off[e], c = s_off[e + 1] - s;
      for (int ro = 0; ro < c; ro += 128)
        t128[n1++] = make_int4(e, s + ro, (c - ro) < 128 ? (c - ro) : 128, 0);
    }
    for (; n1 < MAXT128; n1++) t128[n1] = make_int4(-1, 0, 0, 0);
  }
  __syncthreads();
  const int r = r_sh;  // rowtiles, 16..19
  for (int i = threadIdx.x; i < 16 * r; i += 256)
    t256[i] = make_int4(rtE[i >> 4], rtP[i >> 4], rtC[i >> 4], (i & 15) * 256);
  {
    const int b = threadIdx.x;
    const int ru = r - 16;
    const int xcd = b & 7, s = b >> 3;
    const int rt_ = 4 * (xcd >> 1) + (s >> 3);
    const int nt_ = 8 * (xcd & 1) + (s & 7);
    sched[b * 3 + 0] = make_int4(rt_ * 16 + nt_, 0, 16, 0);
    int sgi = 1, u0 = b * ru, u1 = u0 + ru;
    while (u0 < u1) {
      int tI = 256 + (u0 >> 4), q0 = u0 & 15;
      int avail = 16 - q0, want = u1 - u0;
      int take = want < avail ? want : avail;
      sched[b * 3 + sgi] = make_int4(tI, q0, take, 0);
      sgi++; u0 += take;
    }
    for (; sgi < 3; sgi++) sched[b * 3 + sgi] = make_int4(-1, 0, 0, 0);
  }
}

// Merged: zero remainder-tile output regions (first 768 blocks) + cast W
// (fp32->bf16, 16B stores) + gather-cast x into expert-sorted order.
// Write sets disjoint (out vs wb/xg); stream order guarantees both complete
// before gemm8p launches.
__global__ void convert_zero(const float4* __restrict__ w4, const float* __restrict__ x,
                             const int* __restrict__ perm, const int* __restrict__ meta,
                             const int4* __restrict__ t256, float* __restrict__ out,
                             ushort8* __restrict__ wb8, ushort8* __restrict__ xg8) {
  // --- zero_rem part (blocks 0..767: 48 tiles x 16 row-groups) ---
  if (blockIdx.x < 768) {
    const int tI = 256 + (int)blockIdx.x / 16;
    if (tI < meta[0]) {
      const int4 td = t256[tI];
      const int rt = (blockIdx.x & 15) * 16 + ((int)threadIdx.x >> 4);
      if (rt < td.z) {
        float4* p = (float4*)(out + (size_t)perm[td.y + rt] * O + td.w) + (threadIdx.x & 15) * 4;
        const float4 z = {0.f, 0.f, 0.f, 0.f};
        p[0] = z; p[1] = z; p[2] = z; p[3] = z;
      }
    }
  }
  // --- convert part: W then x, branch-free grid-stride, 32B read/16B write ---
  const size_t NW8 = (size_t)E * O * K / 8;   // 8388608
  const size_t NX8 = (size_t)T * K / 8;       // 2097152
  const size_t stride = (size_t)gridDim.x * blockDim.x;
  const size_t t0 = (size_t)blockIdx.x * blockDim.x + threadIdx.x;
  for (size_t i = t0; i < NW8; i += stride) {
    float4 a = w4[2 * i], b = w4[2 * i + 1];
    wb8[i] = cvt8(a, b);
  }
  for (size_t j = t0; j < NX8; j += stride) {
    int p = (int)(j >> 9);            // K/8 = 512 ushort8 per row
    int c = (int)(j & 511);
    const float4* src = (const float4*)(x + (size_t)perm[p] * K) + 2 * c;
    xg8[j] = cvt8(src[0], src[1]);
  }
}

// ---------------- persistent 256x256 minimal-sync grouped GEMM (16x16x32) ---
// 256 blocks (1/CU), each runs <=3 (tile, K-range) segments from sched.
// LDS per buffer: 4 slabs of 16KB [A.kh0][A.kh1][B.kh0][B.kh1], 2 buffers.
// Slab = [256 rows][32 bf16] as 1024 16B-slots, 2-row-block XOR swizzle.
// MINIMAL SYNC: exactly 2 {counted-vmcnt; barrier} points per K-tile (the
// publications of the two staged halves). No lgkm drains: compiler emits
// per-dependency counted lgkmcnt; wave skew overlaps one wave's LDS read
// storm with co-resident waves' MFMA storms (setprio arbitrates).
__global__ __launch_bounds__(512, 2)
void gemm8p(const unsigned short* __restrict__ xg, const unsigned short* __restrict__ wbb,
            const int* __restrict__ perm, const int4* __restrict__ t256,
            const int4* __restrict__ sched, float* __restrict__ out) {
  __shared__ unsigned short lds[65536];  // 128 KiB
  const int bid = blockIdx.x;
  const int tid = threadIdx.x;
  const int wid = tid >> 6, lane = tid & 63;
  const int wr = wid >> 2, wc = wid & 3;  // 2M x 4N waves; per-wave 128x64
  const int kc4 = lane >> 4;
  unsigned short* ldsw = &lds[wid * 512];  // wave-uniform stage base

#define GLL(gp, lp) __builtin_amdgcn_global_load_lds( \
    (const __attribute__((address_space(1))) void*)(gp), \
    (__attribute__((address_space(3))) void*)(lp), 16, 0, 0)
#define STAGE_A(bo, kh, ko) do { \
    GLL(srcA0 + (ko) + (kh) * 32, ldsw + (bo) + (kh) * 8192); \
    GLL(srcA1 + (ko) + (kh) * 32, ldsw + (bo) + (kh) * 8192 + 4096); \
  } while (0)
#define STAGE_B(bo, kh, ko) do { \
    GLL(srcB0 + (ko) + (kh) * 32, ldsw + (bo) + 16384 + (kh) * 8192); \
    GLL(srcB1 + (ko) + (kh) * 32, ldsw + (bo) + 16384 + (kh) * 8192 + 4096); \
  } while (0)
#define LOADA(dst, bo, ks, mh) do { _Pragma("unroll") \
    for (int mi = 0; mi < 4; ++mi) \
      dst[mi] = *(const bf16x8*)&lds[(bo) + (ks) * 8192 + aoff[mh][mi]]; } while (0)
#define LOADB(dst, bo, ks) do { _Pragma("unroll") \
    for (int ni = 0; ni < 4; ++ni) \
      dst[ni] = *(const bf16x8*)&lds[(bo) + 16384 + (ks) * 8192 + boff[ni]]; } while (0)
#define MFMA16(A, B, mh) do { _Pragma("unroll") \
    for (int mi = 0; mi < 4; ++mi) _Pragma("unroll") \
      for (int ni = 0; ni < 4; ++ni) \
        acc[(mh) * 4 + mi][ni] = __builtin_amdgcn_mfma_f32_16x16x32_bf16( \
            A[mi], B[ni], acc[(mh) * 4 + mi][ni], 0, 0, 0); } while (0)
#define BAR() do { __builtin_amdgcn_s_barrier(); asm volatile("" ::: "memory"); } while (0)
#define VM4() asm volatile("s_waitcnt vmcnt(4)" ::: "memory")
#define VM0() asm volatile("s_waitcnt vmcnt(0)" ::: "memory")
#define PRIO1() __builtin_amdgcn_s_setprio(1)
#define PRIO0() __builtin_amdgcn_s_setprio(0)

// One K-tile = 2 scheduling regions, each ends with its half-publication.
// Sync#1 drains prev-tile A1,B1 (cur.kh1 published for half 2).
// Sync#2 drains this tile's A0x,B0x (nxt.kh0 published for next tile).
#define KTILE(C, X, koe) do { \
    const int ko = (koe); \
    LOADA(afP, C, 0, 0); LOADB(bfP, C, 0); \
    STAGE_A(X, 0, ko); \
    PRIO1(); MFMA16(afP, bfP, 0); PRIO0(); \
    LOADA(afQ, C, 0, 1); \
    STAGE_B(X, 0, ko); \
    PRIO1(); MFMA16(afQ, bfP, 1); PRIO0(); \
    VM4(); BAR(); \
    LOADA(afP, C, 1, 0); LOADB(bfQ, C, 1); \
    STAGE_A(X, 1, ko); \
    PRIO1(); MFMA16(afP, bfQ, 0); PRIO0(); \
    LOADA(afQ, C, 1, 1); \
    STAGE_B(X, 1, ko); \
    PRIO1(); MFMA16(afQ, bfQ, 1); PRIO0(); \
    VM4(); BAR(); \
  } while (0)

  // swizzled fragment offsets (ushort units) — segment-invariant
  int aoff[2][4], boff[4];
#pragma unroll
  for (int mh = 0; mh < 2; ++mh)
#pragma unroll
    for (int mi = 0; mi < 4; ++mi) {
      int r = wr * 128 + mh * 64 + mi * 16 + (lane & 15);
      aoff[mh][mi] = (((r >> 1) << 3) + (((((r & 1) << 2) | kc4)) ^ ((r >> 1) & 7))) * 8;
    }
#pragma unroll
  for (int ni = 0; ni < 4; ++ni) {
    int r = wc * 64 + ni * 16 + (lane & 15);
    boff[ni] = (((r >> 1) << 3) + (((((r & 1) << 2) | kc4)) ^ ((r >> 1) & 7))) * 8;
  }

  for (int sg = 0; sg < 3; ++sg) {
    const int4 sd = sched[bid * 3 + sg];
    if (sd.x < 0) break;
    const int4 td = t256[sd.x];
    const int e = td.x, p0 = td.y, rc = td.z, n0 = td.w;
    const int kt0 = sd.y << 2;   // first BK-tile
    const int nt = sd.z << 2;    // BK-tiles in segment (multiple of 4)

    // staging source decode (slot -> logical row/c4, inverse of read swizzle)
    const unsigned short *srcA0, *srcA1, *srcB0, *srcB1;
    {
      const unsigned short* wB = wbb + (size_t)e * O * K + (size_t)n0 * K;
      int s0 = tid, s1 = 512 + tid;
      int b0 = s0 >> 3, v0 = (s0 & 7) ^ (b0 & 7);
      int r0 = b0 * 2 + (v0 >> 2), c0 = v0 & 3;
      int b1 = s1 >> 3, v1 = (s1 & 7) ^ (b1 & 7);
      int r1 = b1 * 2 + (v1 >> 2), c1 = v1 & 3;
      int ra0 = r0 < rc ? r0 : rc - 1;
      int ra1 = r1 < rc ? r1 : rc - 1;
      srcA0 = xg + (size_t)(p0 + ra0) * K + c0 * 8;
      srcA1 = xg + (size_t)(p0 + ra1) * K + c1 * 8;
      srcB0 = wB + (size_t)r0 * K + c0 * 8;
      srcB1 = wB + (size_t)r1 * K + c1 * 8;
    }

    f32x4 acc[8][4] = {};
    bf16x8 afP[4], afQ[4], bfP[4], bfQ[4];

    const int kb = kt0 << 6;
    STAGE_A(0, 0, kb); STAGE_B(0, 0, kb);
    STAGE_A(0, 1, kb); STAGE_B(0, 1, kb);
    VM4(); BAR();   // kh0 published; kh1 (A1,B1) drains at first in-loop sync

    for (int tp = 0; tp < nt; tp += 2) {
      KTILE(0, 32768, ((tp + 1 < nt ? tp + 1 : tp) + kt0) << 6);
      KTILE(32768, 0, ((tp + 2 < nt ? tp + 2 : tp + 1) + kt0) << 6);
    }
    VM0();  // drain stale prefetch before epilogue / next segment's staging

    // epilogue: C layout col=lane&15, row=(lane>>4)*4+reg
    if (sd.z == 16) {
#pragma unroll
      for (int mh = 0; mh < 2; ++mh)
#pragma unroll
        for (int mi = 0; mi < 4; ++mi) {
          const int rbase = wr * 128 + mh * 64 + mi * 16 + (lane >> 4) * 4;
#pragma unroll
          for (int reg = 0; reg < 4; ++reg) {
            const int pr = rbase + reg;
            if (pr < rc) {
              float* orow = out + (size_t)perm[p0 + pr] * O + n0 + wc * 64 + (lane & 15);
#pragma unroll
              for (int ni = 0; ni < 4; ++ni) orow[ni * 16] = acc[mh * 4 + mi][ni][reg];
            }
          }
        }
    } else {
#pragma unroll
      for (int mh = 0; mh < 2; ++mh)
#pragma unroll
        for (int mi = 0; mi < 4; ++mi) {
          const int rbase = wr * 128 + mh * 64 + mi * 16 + (lane >> 4) * 4;
#pragma unroll
          for (int reg = 0; reg < 4; ++reg) {
            const int pr = rbase + reg;
            if (pr < rc) {
              float* orow = out + (size_t)perm[p0 + pr] * O + n0 + wc * 64 + (lane & 15);
#pragma unroll
              for (int ni = 0; ni < 4; ++ni)
                unsafeAtomicAdd(&orow[ni * 16], acc[mh * 4 + mi][ni][reg]);
            }
          }
        }
    }
  }
}

// ---------------- fallback (small ws): 128x128 fp32-source reg-staged ----------------
__global__ __launch_bounds__(256)
void gemm_fb(const float* __restrict__ xf, const float* __restrict__ wf,
             const int* __restrict__ perm, const int4* __restrict__ tiles,
             float* __restrict__ out) {
  __shared__ unsigned short lds_a[128 * 64];
  __shared__ unsigned short lds_b[128 * 64];
  const int4 td = tiles[blockIdx.x];
  if (td.x < 0) return;
  const int e = td.x, p0 = td.y, rc = td.z;
  const int n0 = blockIdx.y * 128;
  const int wave = threadIdx.x >> 6, lane = threadIdx.x & 63;
  const int wr = wave >> 1, wc = wave & 1;
  f32x4 acc[4][4] = {};
  const float* wf_base = wf + (size_t)e * O * K + (size_t)n0 * K;
  for (int k0 = 0; k0 < K; k0 += 64) {
    if (k0) __syncthreads();
#pragma unroll
    for (int i = 0; i < 8; i++) {
      int l4 = i * 256 + (int)threadIdx.x;
      int row = l4 >> 4;
      int c4 = (l4 & 15) << 2;
      int ra = row < rc ? row : (rc - 1);
      const float4 va = *(const float4*)(xf + (size_t)perm[p0 + ra] * K + k0 + c4);
      *(ushort4*)&lds_a[row * 64 + c4] = make_ushort4(f2bf(va.x), f2bf(va.y), f2bf(va.z), f2bf(va.w));
      const float4 vb = *(const float4*)(wf_base + (size_t)row * K + k0 + c4);
      *(ushort4*)&lds_b[row * 64 + c4] = make_ushort4(f2bf(vb.x), f2bf(vb.y), f2bf(vb.z), f2bf(vb.w));
    }
    __syncthreads();
#pragma unroll
    for (int ks = 0; ks < 2; ks++) {
      bf16x8 a2[4], b2[4];
#pragma unroll
      for (int mi = 0; mi < 4; mi++)
        a2[mi] = *(const bf16x8*)&lds_a[(wr * 64 + mi * 16 + (lane & 15)) * 64 + ks * 32 + (lane >> 4) * 8];
#pragma unroll
      for (int ni = 0; ni < 4; ni++)
        b2[ni] = *(const bf16x8*)&lds_b[(wc * 64 + ni * 16 + (lane & 15)) * 64 + ks * 32 + (lane >> 4) * 8];
#pragma unroll
      for (int mi = 0; mi < 4; mi++)
#pragma unroll
        for (int ni = 0; ni < 4; ni++)
          acc[mi][ni] = __builtin_amdgcn_mfma_f32_16x16x32_bf16(a2[mi], b2[ni], acc[mi][ni], 0, 0, 0);
    }
  }
#pragma unroll
  for (int mi = 0; mi < 4; mi++) {
    const int rb = wr * 64 + mi * 16 + (lane >> 4) * 4;
#pragma unroll
    for (int reg = 0; reg < 4; reg++) {
      const int rt = rb + reg;
      if (rt < rc) {
        float* orow = out + (size_t)perm[p0 + rt] * O + n0 + wc * 64 + (lane & 15);
#pragma unroll
        for (int ni = 0; ni < 4; ni++) orow[ni * 16] = acc[mi][ni][reg];
      }
    }
  }
}

extern "C" void kernel_launch(void* const* d_in, const int* in_sizes, int n_in,
                              void* d_out, int out_size, void* d_ws, size_t ws_size,
                              hipStream_t stream) {
  const float* x = (const float*)d_in[0];
  const float* w = (const float*)d_in[1];
  const int* idx = (const int*)d_in[2];
  float* out = (float*)d_out;
  char* ws = (char*)d_ws;

  int* perm = (int*)ws;                        // 16 KB
  int* meta = (int*)(ws + 16384);              // 16 B
  int4* t256 = (int4*)(ws + 16640);            // 4864 B
  int4* t128 = (int4*)(ws + 22528);            // 560 B
  int4* sched = (int4*)(ws + 24576);           // 12 KB
  unsigned short* xg = (unsigned short*)(ws + 65536);          // 32 MB bf16
  unsigned short* wb = xg + (size_t)T * K;                     // 128 MB bf16
  const size_t need = 65536 + (size_t)T * K * 2 + (size_t)E * O * K * 2;

  build_meta<<<1, 256, 0, stream>>>(idx, perm, meta, t256, t128, sched);
  if (ws_size >= need) {
    convert_zero<<<4096, 256, 0, stream>>>((const float4*)w, x, perm, meta, t256,
                                           out, (ushort8*)wb, (ushort8*)xg);
    gemm8p<<<256, 512, 0, stream>>>(xg, wb, perm, t256, sched, out);
  } else {
    gemm_fb<<<dim3(MAXT128, 32), 256, 0, stream>>>(x, w, perm, t128, out);
  }
}

// Round 16
// 267.959 us; speedup vs baseline: 1.0891x; 1.0011x over previous
//
#include <hip/hip_runtime.h>

#define T 4096
#define K 4096
#define O 4096
#define E 4
#define BK 64
#define MAXT128 35

typedef __attribute__((ext_vector_type(8))) short bf16x8;
typedef __attribute__((ext_vector_type(8))) unsigned short ushort8;
typedef __attribute__((ext_vector_type(4))) float f32x4;

__device__ __forceinline__ unsigned short f2bf(float f) {
  unsigned int u = __float_as_uint(f);
  u += 0x7fffu + ((u >> 16) & 1u);  // RNE
  return (unsigned short)(u >> 16);
}

__device__ __forceinline__ ushort8 cvt8(float4 a, float4 b) {
  ushort8 r;
  r[0] = f2bf(a.x); r[1] = f2bf(a.y); r[2] = f2bf(a.z); r[3] = f2bf(a.w);
  r[4] = f2bf(b.x); r[5] = f2bf(b.y); r[6] = f2bf(b.z); r[7] = f2bf(b.w);
  return r;
}

// One block, 256 threads. perm, tile tables, persistent schedule
// (XCD 4x8 region map + remainder K-units; K-unit = 256 k = 4 BK-tiles).
__global__ void build_meta(const int* __restrict__ idx, int* __restrict__ perm,
                           int* __restrict__ meta, int4* __restrict__ t256,
                           int4* __restrict__ t128, int4* __restrict__ sched) {
  const int wave = threadIdx.x >> 6;
  const int lane = threadIdx.x & 63;
  __shared__ int s_off[E + 1];
  __shared__ int rtE[20], rtP[20], rtC[20];
  __shared__ int r_sh;
  int total = 0;
  for (int t0 = 0; t0 < T; t0 += 64)
    total += __popcll(__ballot(idx[t0 + lane] == wave));
  if (lane == 0) s_off[wave + 1] = total;
  __syncthreads();
  if (threadIdx.x == 0) {
    s_off[0] = 0;
    for (int e = 0; e < E; e++) s_off[e + 1] += s_off[e];
  }
  __syncthreads();
  int base = s_off[wave];
  const unsigned long long below = (1ull << lane) - 1ull;
  for (int t0 = 0; t0 < T; t0 += 64) {
    int e = idx[t0 + lane];
    unsigned long long m = __ballot(e == wave);
    if (e == wave) perm[base + __popcll(m & below)] = t0 + lane;
    base += __popcll(m);
  }
  if (threadIdx.x == 0) {
    int n = 0;
    for (int e = 0; e < E; e++) {
      int s = s_off[e], c = s_off[e + 1] - s;
      for (int ro = 0; ro < c; ro += 256) {
        rtE[n] = e; rtP[n] = s + ro; rtC[n] = (c - ro) < 256 ? (c - ro) : 256; n++;
      }
    }
    r_sh = n;
    meta[0] = n * 16;
    int n1 = 0;
    for (int e = 0; e < E; e++) {
      int s = s_off[e], c = s_off[e + 1] - s;
      for (int ro = 0; ro < c; ro += 128)
        t128[n1++] = make_int4(e, s + ro, (c - ro) < 128 ? (c - ro) : 128, 0);
    }
    for (; n1 < MAXT128; n1++) t128[n1] = make_int4(-1, 0, 0, 0);
  }
  __syncthreads();
  const int r = r_sh;  // rowtiles, 16..19
  for (int i = threadIdx.x; i < 16 * r; i += 256)
    t256[i] = make_int4(rtE[i >> 4], rtP[i >> 4], rtC[i >> 4], (i & 15) * 256);
  {
    const int b = threadIdx.x;
    const int ru = r - 16;
    const int xcd = b & 7, s = b >> 3;
    const int rt_ = 4 * (xcd >> 1) + (s >> 3);
    const int nt_ = 8 * (xcd & 1) + (s & 7);
    sched[b * 3 + 0] = make_int4(rt_ * 16 + nt_, 0, 16, 0);
    int sgi = 1, u0 = b * ru, u1 = u0 + ru;
    while (u0 < u1) {
      int tI = 256 + (u0 >> 4), q0 = u0 & 15;
      int avail = 16 - q0, want = u1 - u0;
      int take = want < avail ? want : avail;
      sched[b * 3 + sgi] = make_int4(tI, q0, take, 0);
      sgi++; u0 += take;
    }
    for (; sgi < 3; sgi++) sched[b * 3 + sgi] = make_int4(-1, 0, 0, 0);
  }
}

// Merged: zero remainder-tile output regions (first 768 blocks) + cast W
// (fp32->bf16, 16B stores) + gather-cast x into expert-sorted order.
__global__ void convert_zero(const float4* __restrict__ w4, const float* __restrict__ x,
                             const int* __restrict__ perm, const int* __restrict__ meta,
                             const int4* __restrict__ t256, float* __restrict__ out,
                             ushort8* __restrict__ wb8, ushort8* __restrict__ xg8) {
  // --- zero_rem part (blocks 0..767: 48 tiles x 16 row-groups) ---
  if (blockIdx.x < 768) {
    const int tI = 256 + (int)blockIdx.x / 16;
    if (tI < meta[0]) {
      const int4 td = t256[tI];
      const int rt = (blockIdx.x & 15) * 16 + ((int)threadIdx.x >> 4);
      if (rt < td.z) {
        float4* p = (float4*)(out + (size_t)perm[td.y + rt] * O + td.w) + (threadIdx.x & 15) * 4;
        const float4 z = {0.f, 0.f, 0.f, 0.f};
        p[0] = z; p[1] = z; p[2] = z; p[3] = z;
      }
    }
  }
  // --- convert part: W then x, branch-free grid-stride, 32B read/16B write ---
  const size_t NW8 = (size_t)E * O * K / 8;
  const size_t NX8 = (size_t)T * K / 8;
  const size_t stride = (size_t)gridDim.x * blockDim.x;
  const size_t t0 = (size_t)blockIdx.x * blockDim.x + threadIdx.x;
  for (size_t i = t0; i < NW8; i += stride) {
    float4 a = w4[2 * i], b = w4[2 * i + 1];
    wb8[i] = cvt8(a, b);
  }
  for (size_t j = t0; j < NX8; j += stride) {
    int p = (int)(j >> 9);
    int c = (int)(j & 511);
    const float4* src = (const float4*)(x + (size_t)perm[p] * K) + 2 * c;
    xg8[j] = cvt8(src[0], src[1]);
  }
}

// ---------------- persistent 256x256 minimal-sync grouped GEMM (16x16x32) ---
// 256 blocks (1/CU), each runs <=3 (tile, K-range) segments from sched.
// LDS per buffer: 4 slabs of 16KB [A.kh0][A.kh1][B.kh0][B.kh1], 2 buffers.
// Slab = [256 rows][32 bf16] as 1024 16B-slots, 2-row-block XOR swizzle.
// MINIMAL SYNC: exactly 2 {counted-vmcnt; barrier} points per K-tile.
__global__ __launch_bounds__(512, 2)
void gemm8p(const unsigned short* __restrict__ xg, const unsigned short* __restrict__ wbb,
            const int* __restrict__ perm, const int4* __restrict__ t256,
            const int4* __restrict__ sched, float* __restrict__ out) {
  __shared__ unsigned short lds[65536];  // 128 KiB
  const int bid = blockIdx.x;
  const int tid = threadIdx.x;
  const int wid = tid >> 6, lane = tid & 63;
  const int wr = wid >> 2, wc = wid & 3;  // 2M x 4N waves; per-wave 128x64
  const int kc4 = lane >> 4;
  unsigned short* ldsw = &lds[wid * 512];  // wave-uniform stage base

#define GLL(gp, lp) __builtin_amdgcn_global_load_lds( \
    (const __attribute__((address_space(1))) void*)(gp), \
    (__attribute__((address_space(3))) void*)(lp), 16, 0, 0)
#define STAGE_A(bo, kh, ko) do { \
    GLL(srcA0 + (ko) + (kh) * 32, ldsw + (bo) + (kh) * 8192); \
    GLL(srcA1 + (ko) + (kh) * 32, ldsw + (bo) + (kh) * 8192 + 4096); \
  } while (0)
#define STAGE_B(bo, kh, ko) do { \
    GLL(srcB0 + (ko) + (kh) * 32, ldsw + (bo) + 16384 + (kh) * 8192); \
    GLL(srcB1 + (ko) + (kh) * 32, ldsw + (bo) + 16384 + (kh) * 8192 + 4096); \
  } while (0)
#define LOADA(dst, bo, ks, mh) do { _Pragma("unroll") \
    for (int mi = 0; mi < 4; ++mi) \
      dst[mi] = *(const bf16x8*)&lds[(bo) + (ks) * 8192 + aoff[mh][mi]]; } while (0)
#define LOADB(dst, bo, ks) do { _Pragma("unroll") \
    for (int ni = 0; ni < 4; ++ni) \
      dst[ni] = *(const bf16x8*)&lds[(bo) + 16384 + (ks) * 8192 + boff[ni]]; } while (0)
#define MFMA16(A, B, mh) do { _Pragma("unroll") \
    for (int mi = 0; mi < 4; ++mi) _Pragma("unroll") \
      for (int ni = 0; ni < 4; ++ni) \
        acc[(mh) * 4 + mi][ni] = __builtin_amdgcn_mfma_f32_16x16x32_bf16( \
            A[mi], B[ni], acc[(mh) * 4 + mi][ni], 0, 0, 0); } while (0)
#define BAR() do { __builtin_amdgcn_s_barrier(); asm volatile("" ::: "memory"); } while (0)
#define VM4() asm volatile("s_waitcnt vmcnt(4)" ::: "memory")
#define VM0() asm volatile("s_waitcnt vmcnt(0)" ::: "memory")
#define PRIO1() __builtin_amdgcn_s_setprio(1)
#define PRIO0() __builtin_amdgcn_s_setprio(0)

#define KTILE(C, X, koe) do { \
    const int ko = (koe); \
    LOADA(afP, C, 0, 0); LOADB(bfP, C, 0); \
    STAGE_A(X, 0, ko); \
    PRIO1(); MFMA16(afP, bfP, 0); PRIO0(); \
    LOADA(afQ, C, 0, 1); \
    STAGE_B(X, 0, ko); \
    PRIO1(); MFMA16(afQ, bfP, 1); PRIO0(); \
    VM4(); BAR(); \
    LOADA(afP, C, 1, 0); LOADB(bfQ, C, 1); \
    STAGE_A(X, 1, ko); \
    PRIO1(); MFMA16(afP, bfQ, 0); PRIO0(); \
    LOADA(afQ, C, 1, 1); \
    STAGE_B(X, 1, ko); \
    PRIO1(); MFMA16(afQ, bfQ, 1); PRIO0(); \
    VM4(); BAR(); \
  } while (0)

  // swizzled fragment offsets (ushort units) — segment-invariant
  int aoff[2][4], boff[4];
#pragma unroll
  for (int mh = 0; mh < 2; ++mh)
#pragma unroll
    for (int mi = 0; mi < 4; ++mi) {
      int r = wr * 128 + mh * 64 + mi * 16 + (lane & 15);
      aoff[mh][mi] = (((r >> 1) << 3) + (((((r & 1) << 2) | kc4)) ^ ((r >> 1) & 7))) * 8;
    }
#pragma unroll
  for (int ni = 0; ni < 4; ++ni) {
    int r = wc * 64 + ni * 16 + (lane & 15);
    boff[ni] = (((r >> 1) << 3) + (((((r & 1) << 2) | kc4)) ^ ((r >> 1) & 7))) * 8;
  }

  for (int sg = 0; sg < 3; ++sg) {
    const int4 sd = sched[bid * 3 + sg];
    if (sd.x < 0) break;
    const int4 td = t256[sd.x];
    const int e = td.x, p0 = td.y, rc = td.z, n0 = td.w;
    const int kt0 = sd.y << 2;   // first BK-tile
    const int nt = sd.z << 2;    // BK-tiles in segment (multiple of 4)

    // staging source decode (slot -> logical row/c4, inverse of read swizzle)
    const unsigned short *srcA0, *srcA1, *srcB0, *srcB1;
    {
      const unsigned short* wB = wbb + (size_t)e * O * K + (size_t)n0 * K;
      int s0 = tid, s1 = 512 + tid;
      int b0 = s0 >> 3, v0 = (s0 & 7) ^ (b0 & 7);
      int r0 = b0 * 2 + (v0 >> 2), c0 = v0 & 3;
      int b1 = s1 >> 3, v1 = (s1 & 7) ^ (b1 & 7);
      int r1 = b1 * 2 + (v1 >> 2), c1 = v1 & 3;
      int ra0 = r0 < rc ? r0 : rc - 1;
      int ra1 = r1 < rc ? r1 : rc - 1;
      srcA0 = xg + (size_t)(p0 + ra0) * K + c0 * 8;
      srcA1 = xg + (size_t)(p0 + ra1) * K + c1 * 8;
      srcB0 = wB + (size_t)r0 * K + c0 * 8;
      srcB1 = wB + (size_t)r1 * K + c1 * 8;
    }

    f32x4 acc[8][4] = {};
    bf16x8 afP[4], afQ[4], bfP[4], bfQ[4];

    const int kb = kt0 << 6;
    STAGE_A(0, 0, kb); STAGE_B(0, 0, kb);
    STAGE_A(0, 1, kb); STAGE_B(0, 1, kb);
    VM4(); BAR();   // kh0 published; kh1 (A1,B1) drains at first in-loop sync

    for (int tp = 0; tp < nt; tp += 2) {
      KTILE(0, 32768, ((tp + 1 < nt ? tp + 1 : tp) + kt0) << 6);
      KTILE(32768, 0, ((tp + 2 < nt ? tp + 2 : tp + 1) + kt0) << 6);
    }
    VM0();  // drain stale prefetch before epilogue / next segment's staging

    // epilogue: C layout col=lane&15, row=(lane>>4)*4+reg
    if (sd.z == 16) {
#pragma unroll
      for (int mh = 0; mh < 2; ++mh)
#pragma unroll
        for (int mi = 0; mi < 4; ++mi) {
          const int rbase = wr * 128 + mh * 64 + mi * 16 + (lane >> 4) * 4;
#pragma unroll
          for (int reg = 0; reg < 4; ++reg) {
            const int pr = rbase + reg;
            if (pr < rc) {
              float* orow = out + (size_t)perm[p0 + pr] * O + n0 + wc * 64 + (lane & 15);
#pragma unroll
              for (int ni = 0; ni < 4; ++ni) orow[ni * 16] = acc[mh * 4 + mi][ni][reg];
            }
          }
        }
    } else {
#pragma unroll
      for (int mh = 0; mh < 2; ++mh)
#pragma unroll
        for (int mi = 0; mi < 4; ++mi) {
          const int rbase = wr * 128 + mh * 64 + mi * 16 + (lane >> 4) * 4;
#pragma unroll
          for (int reg = 0; reg < 4; ++reg) {
            const int pr = rbase + reg;
            if (pr < rc) {
              float* orow = out + (size_t)perm[p0 + pr] * O + n0 + wc * 64 + (lane & 15);
#pragma unroll
              for (int ni = 0; ni < 4; ++ni)
                unsafeAtomicAdd(&orow[ni * 16], acc[mh * 4 + mi][ni][reg]);
            }
          }
        }
    }
  }
}

// ---------------- fallback (small ws): 128x128 fp32-source reg-staged ----------------
__global__ __launch_bounds__(256)
void gemm_fb(const float* __restrict__ xf, const float* __restrict__ wf,
             const int* __restrict__ perm, const int4* __restrict__ tiles,
             float* __restrict__ out) {
  __shared__ unsigned short lds_a[128 * 64];
  __shared__ unsigned short lds_b[128 * 64];
  const int4 td = tiles[blockIdx.x];
  if (td.x < 0) return;
  const int e = td.x, p0 = td.y, rc = td.z;
  const int n0 = blockIdx.y * 128;
  const int wave = threadIdx.x >> 6, lane = threadIdx.x & 63;
  const int wr = wave >> 1, wc = wave & 1;
  f32x4 acc[4][4] = {};
  const float* wf_base = wf + (size_t)e * O * K + (size_t)n0 * K;
  for (int k0 = 0; k0 < K; k0 += 64) {
    if (k0) __syncthreads();
#pragma unroll
    for (int i = 0; i < 8; i++) {
      int l4 = i * 256 + (int)threadIdx.x;
      int row = l4 >> 4;
      int c4 = (l4 & 15) << 2;
      int ra = row < rc ? row : (rc - 1);
      const float4 va = *(const float4*)(xf + (size_t)perm[p0 + ra] * K + k0 + c4);
      *(ushort4*)&lds_a[row * 64 + c4] = make_ushort4(f2bf(va.x), f2bf(va.y), f2bf(va.z), f2bf(va.w));
      const float4 vb = *(const float4*)(wf_base + (size_t)row * K + k0 + c4);
      *(ushort4*)&lds_b[row * 64 + c4] = make_ushort4(f2bf(vb.x), f2bf(vb.y), f2bf(vb.z), f2bf(vb.w));
    }
    __syncthreads();
#pragma unroll
    for (int ks = 0; ks < 2; ks++) {
      bf16x8 a2[4], b2[4];
#pragma unroll
      for (int mi = 0; mi < 4; mi++)
        a2[mi] = *(const bf16x8*)&lds_a[(wr * 64 + mi * 16 + (lane & 15)) * 64 + ks * 32 + (lane >> 4) * 8];
#pragma unroll
      for (int ni = 0; ni < 4; ni++)
        b2[ni] = *(const bf16x8*)&lds_b[(wc * 64 + ni * 16 + (lane & 15)) * 64 + ks * 32 + (lane >> 4) * 8];
#pragma unroll
      for (int mi = 0; mi < 4; mi++)
#pragma unroll
        for (int ni = 0; ni < 4; ni++)
          acc[mi][ni] = __builtin_amdgcn_mfma_f32_16x16x32_bf16(a2[mi], b2[ni], acc[mi][ni], 0, 0, 0);
    }
  }
#pragma unroll
  for (int mi = 0; mi < 4; mi++) {
    const int rb = wr * 64 + mi * 16 + (lane >> 4) * 4;
#pragma unroll
    for (int reg = 0; reg < 4; reg++) {
      const int rt = rb + reg;
      if (rt < rc) {
        float* orow = out + (size_t)perm[p0 + rt] * O + n0 + wc * 64 + (lane & 15);
#pragma unroll
        for (int ni = 0; ni < 4; ni++) orow[ni * 16] = acc[mi][ni][reg];
      }
    }
  }
}

extern "C" void kernel_launch(void* const* d_in, const int* in_sizes, int n_in,
                              void* d_out, int out_size, void* d_ws, size_t ws_size,
                              hipStream_t stream) {
  const float* x = (const float*)d_in[0];
  const float* w = (const float*)d_in[1];
  const int* idx = (const int*)d_in[2];
  float* out = (float*)d_out;
  char* ws = (char*)d_ws;

  int* perm = (int*)ws;                        // 16 KB
  int* meta = (int*)(ws + 16384);              // 16 B
  int4* t256 = (int4*)(ws + 16640);            // 4864 B
  int4* t128 = (int4*)(ws + 22528);            // 560 B
  int4* sched = (int4*)(ws + 24576);           // 12 KB
  unsigned short* xg = (unsigned short*)(ws + 65536);          // 32 MB bf16
  unsigned short* wb = xg + (size_t)T * K;                     // 128 MB bf16
  const size_t need = 65536 + (size_t)T * K * 2 + (size_t)E * O * K * 2;

  build_meta<<<1, 256, 0, stream>>>(idx, perm, meta, t256, t128, sched);
  if (ws_size >= need) {
    convert_zero<<<2048, 256, 0, stream>>>((const float4*)w, x, perm, meta, t256,
                                           out, (ushort8*)wb, (ushort8*)xg);
    gemm8p<<<256, 512, 0, stream>>>(xg, wb, perm, t256, sched, out);
  } else {
    gemm_fb<<<dim3(MAXT128, 32), 256, 0, stream>>>(x, w, perm, t128, out);
  }
}